// Round 3
// baseline (941.854 us; speedup 1.0000x reference)
//
#include <hip/hip_runtime.h>
#include <hip/hip_bf16.h>

// Problem constants
#define NBANDS 5
#define BATCH  512
#define KQN    64     // queries per sample
#define DM     200    // model dim
#define NHEAD  4
#define HD     50     // head dim
#define HIDW   512    // router hidden
#define TKV    320    // NBANDS*KQN keys
#define FIN    64000  // NBANDS*KQN*DM
#define KSPLIT 20
#define KCH    3200   // FIN/KSPLIT
#define RCH    50     // KCH/64 chunks per block
#define NTT    13     // N-tiles of 16 covering 200 (13*16=208)
#define KST    7      // K-steps of 32 covering 200 (7*32=224)
#define NTKV   25     // N-tiles of 16 covering 400
#define PLANE_ELEMS (KST * NTT * 64 * 8)   // 46592 ushorts = 93,184 B

typedef __bf16  bf16x8 __attribute__((ext_vector_type(8)));
typedef float   f32x4  __attribute__((ext_vector_type(4)));

static __device__ inline unsigned short f2bf(float f) {
    __hip_bfloat16 h = __float2bfloat16(f);
    return *reinterpret_cast<unsigned short*>(&h);
}
static __device__ inline float bf2f(unsigned short u) {
    union { unsigned int i; float f; } x;
    x.i = ((unsigned int)u) << 16;
    return x.f;
}
static __device__ inline bf16x8 bf8zero() {
    union { bf16x8 v; unsigned int u[4]; } z;
    z.u[0] = z.u[1] = z.u[2] = z.u[3] = 0u;
    return z.v;
}
// Markidis split of 8 consecutive fp32 into hi/lo bf16x8
static __device__ inline void split8(const float4& a, const float4& b,
                                     bf16x8& hi, bf16x8& lo) {
    union { bf16x8 v; unsigned short u[8]; } H, L;
    const float xs[8] = {a.x, a.y, a.z, a.w, b.x, b.y, b.z, b.w};
#pragma unroll
    for (int i = 0; i < 8; ++i) {
        H.u[i] = f2bf(xs[i]);
        L.u[i] = f2bf(xs[i] - bf2f(H.u[i]));
    }
    hi = H.v; lo = L.v;
}
// plain bf16 round of 8 consecutive fp32
static __device__ inline bf16x8 round8(const float4& a, const float4& b) {
    union { bf16x8 v; unsigned short u[8]; } H;
    const float xs[8] = {a.x, a.y, a.z, a.w, b.x, b.y, b.z, b.w};
#pragma unroll
    for (int i = 0; i < 8; ++i) H.u[i] = f2bf(xs[i]);
    return H.v;
}

// ---------------------------------------------------------------------------
// K1: router GEMM via 3-product split-bf16 MFMA, in-kernel Markidis split of
// both operands. Grid 8x8x20 = 1280 blocks, XCD-clustered so each z-slice's
// 64 (j,b) tiles co-reside on one XCD (slice working set ~262 KB << 4 MB L2).
// acc += Ah*Bh + Ah*Bl + Al*Bh  (fp32 accum; logit err ~1e-5 << top-2 gap)
// ---------------------------------------------------------------------------
__global__ __launch_bounds__(256) void k_router_mfma(
    const float* __restrict__ bands, const float* __restrict__ w1,
    float* __restrict__ part)
{
    __shared__ __align__(16) unsigned short Ah[64][72];
    __shared__ __align__(16) unsigned short Al[64][72];
    __shared__ __align__(16) unsigned short Bh[64][72];
    __shared__ __align__(16) unsigned short Bl[64][72];

    // bijective XCD-cluster swizzle: 1280 blocks = 8 XCD x 160 logical
    const int lin     = (blockIdx.z << 6) + (blockIdx.y << 3) + blockIdx.x;
    const int logical = (lin & 7) * 160 + (lin >> 3);
    const int z   = logical >> 6;          // 0..19
    const int rem = logical & 63;
    const int j0  = (rem & 7) << 6;        // hid tile
    const int b0  = (rem >> 3) << 6;       // batch tile

    const int t  = threadIdx.x;
    const int w  = t >> 6, lane = t & 63;
    const int lm = lane & 15, quad = lane >> 4;
    const int m0 = w * 16;

    const int row0 = t >> 4, c4 = (t & 15) * 4;

    f32x4 acc[4];
#pragma unroll
    for (int nt = 0; nt < 4; ++nt) acc[nt] = (f32x4){0.f, 0.f, 0.f, 0.f};

    const int kbase = z * KCH;
    for (int chunk = 0; chunk < RCH; ++chunk) {
        const int kc = kbase + chunk * 64;
        const int band = kc / 12800;
        const float* abase = bands + (size_t)band * 6540800 + kc + c4;
        const float* bbase = w1 + (size_t)j0 * FIN + kc + c4;
        float4 av[4], bv[4];
#pragma unroll
        for (int r = 0; r < 4; ++r)
            av[r] = *(const float4*)(abase + (size_t)(b0 + row0 + r * 16) * 12800);
#pragma unroll
        for (int r = 0; r < 4; ++r)
            bv[r] = *(const float4*)(bbase + (size_t)(row0 + r * 16) * FIN);
        __syncthreads();   // previous chunk's MFMA LDS reads complete
#pragma unroll
        for (int r = 0; r < 4; ++r) {
            const int row = row0 + r * 16;
            ushort4 hh, ll;
            hh.x = f2bf(av[r].x); ll.x = f2bf(av[r].x - bf2f(hh.x));
            hh.y = f2bf(av[r].y); ll.y = f2bf(av[r].y - bf2f(hh.y));
            hh.z = f2bf(av[r].z); ll.z = f2bf(av[r].z - bf2f(hh.z));
            hh.w = f2bf(av[r].w); ll.w = f2bf(av[r].w - bf2f(hh.w));
            *(ushort4*)&Ah[row][c4] = hh;
            *(ushort4*)&Al[row][c4] = ll;
        }
#pragma unroll
        for (int r = 0; r < 4; ++r) {
            const int row = row0 + r * 16;
            ushort4 hh, ll;
            hh.x = f2bf(bv[r].x); ll.x = f2bf(bv[r].x - bf2f(hh.x));
            hh.y = f2bf(bv[r].y); ll.y = f2bf(bv[r].y - bf2f(hh.y));
            hh.z = f2bf(bv[r].z); ll.z = f2bf(bv[r].z - bf2f(hh.z));
            hh.w = f2bf(bv[r].w); ll.w = f2bf(bv[r].w - bf2f(hh.w));
            *(ushort4*)&Bh[row][c4] = hh;
            *(ushort4*)&Bl[row][c4] = ll;
        }
        __syncthreads();
#pragma unroll
        for (int ks = 0; ks < 2; ++ks) {
            const int ka = ks * 32 + quad * 8;
            const bf16x8 a_h = *(const bf16x8*)&Ah[m0 + lm][ka];
            const bf16x8 a_l = *(const bf16x8*)&Al[m0 + lm][ka];
#pragma unroll
            for (int nt = 0; nt < 4; ++nt) {
                const bf16x8 b_h = *(const bf16x8*)&Bh[nt * 16 + lm][ka];
                const bf16x8 b_l = *(const bf16x8*)&Bl[nt * 16 + lm][ka];
                acc[nt] = __builtin_amdgcn_mfma_f32_16x16x32_bf16(a_h, b_h, acc[nt], 0, 0, 0);
                acc[nt] = __builtin_amdgcn_mfma_f32_16x16x32_bf16(a_l, b_h, acc[nt], 0, 0, 0);
                acc[nt] = __builtin_amdgcn_mfma_f32_16x16x32_bf16(a_h, b_l, acc[nt], 0, 0, 0);
            }
        }
    }
    float* po = part + (size_t)z * (BATCH * HIDW);
#pragma unroll
    for (int nt = 0; nt < 4; ++nt) {
        const int jj = j0 + nt * 16 + lm;
#pragma unroll
        for (int reg = 0; reg < 4; ++reg) {
            const int bb = b0 + m0 + quad * 4 + reg;
            po[(size_t)bb * HIDW + jj] = acc[nt][reg];
        }
    }
}

// ---------------------------------------------------------------------------
// K2: h = relu(sum_z part + b1)
// ---------------------------------------------------------------------------
__global__ __launch_bounds__(256) void k_reduce_relu(
    const float* __restrict__ part, const float* __restrict__ b1,
    float* __restrict__ h)
{
    const int tid = blockIdx.x * 256 + threadIdx.x;  // < BATCH*HIDW
    float s = b1[tid & (HIDW - 1)];
#pragma unroll
    for (int z = 0; z < KSPLIT; ++z) s += part[z * (BATCH * HIDW) + tid];
    h[tid] = fmaxf(s, 0.f);
}

// ---------------------------------------------------------------------------
// K2c: pack wq (ipw rows 0..199) and out_w into FRAGMENT-MAJOR Markidis
// hi/lo bf16 planes: elem idx = ((ks*13+nt)*64 + lane)*8 + e  maps to
// W[nt*16 + (lane&15)][ks*32 + (lane>>4)*8 + e], zero-padded past 200.
// ---------------------------------------------------------------------------
__global__ __launch_bounds__(256) void k_wpack(
    const float* __restrict__ ipw, const float* __restrict__ outw,
    unsigned short* __restrict__ WqHp, unsigned short* __restrict__ WqLp,
    unsigned short* __restrict__ OwHp, unsigned short* __restrict__ OwLp)
{
    const int p = blockIdx.x;          // 0..90 : ks*13+nt
    const int ks = p / NTT, nt = p - ks * NTT;
    const int t = threadIdx.x;
    const int lane = t >> 2, e0 = (t & 3) * 2;
    const int lm = lane & 15, quad = lane >> 4;
    const int row = nt * 16 + lm;
    const int k  = ks * 32 + quad * 8 + e0;
    const float* src = (blockIdx.y == 0) ? ipw : outw;   // wq = ipw rows 0..199
    unsigned short* dh = (blockIdx.y == 0) ? WqHp : OwHp;
    unsigned short* dl = (blockIdx.y == 0) ? WqLp : OwLp;
    float v0 = 0.f, v1 = 0.f;
    if (row < DM && k < DM) {          // k even, so k<200 => k+1<=199 valid
        v0 = src[(size_t)row * DM + k];
        v1 = src[(size_t)row * DM + k + 1];
    }
    const int off = (p << 9) + (lane << 3) + e0;
    const unsigned short h0 = f2bf(v0), h1 = f2bf(v1);
    dh[off]     = h0;
    dh[off + 1] = h1;
    dl[off]     = f2bf(v0 - bf2f(h0));
    dl[off + 1] = f2bf(v1 - bf2f(h1));
}

// ---------------------------------------------------------------------------
// K2d: pack wk|wv (ipw rows 200..599, 400 rows) into ONE fragment-major bf16
// plane (no Markidis — K/V are rounded to bf16 downstream anyway):
// elem ((ks*25+nt)*64 + lane)*8 + e = ipw[200 + nt*16+lm][ks*32+quad*8+e],
// zero past k=200. Plane = 7*25*512 ushorts = 179,200 B (L2-resident).
// ---------------------------------------------------------------------------
__global__ __launch_bounds__(256) void k_wpack_kv(
    const float* __restrict__ ipw, unsigned short* __restrict__ Wkv)
{
    const int p = blockIdx.x;          // 0..174 : ks*25+nt
    const int ks = p / NTKV, nt = p - ks * NTKV;
    const int t = threadIdx.x;
    const int lane = t >> 2, e0 = (t & 3) * 2;
    const int lm = lane & 15, quad = lane >> 4;
    const int row = nt * 16 + lm;                 // 0..399, always valid
    const int k  = ks * 32 + quad * 8 + e0;
    float v0 = 0.f, v1 = 0.f;
    if (k < DM) {
        v0 = ipw[(size_t)(DM + row) * DM + k];
        v1 = ipw[(size_t)(DM + row) * DM + k + 1];
    }
    const int off = (p << 9) + (lane << 3) + e0;
    Wkv[off]     = f2bf(v0);
    Wkv[off + 1] = f2bf(v1);
}

// ---------------------------------------------------------------------------
// K3: logits = h @ w2^T + b2 ; sel = argmax (softmax is monotonic -> skip it)
// ---------------------------------------------------------------------------
__global__ __launch_bounds__(256) void k_argmax(
    const float* __restrict__ h, const float* __restrict__ w2,
    const float* __restrict__ b2, int* __restrict__ sel)
{
    __shared__ float red[NBANDS][256];
    const int b = blockIdx.x, t = threadIdx.x;
    float acc[NBANDS] = {0.f, 0.f, 0.f, 0.f, 0.f};
    for (int j = t; j < HIDW; j += 256) {
        const float hv = h[b * HIDW + j];
#pragma unroll
        for (int n = 0; n < NBANDS; ++n)
            acc[n] = fmaf(hv, w2[n * HIDW + j], acc[n]);
    }
#pragma unroll
    for (int n = 0; n < NBANDS; ++n) red[n][t] = acc[n];
    __syncthreads();
    for (int s = 128; s > 0; s >>= 1) {
        if (t < s) {
#pragma unroll
            for (int n = 0; n < NBANDS; ++n) red[n][t] += red[n][t + s];
        }
        __syncthreads();
    }
    if (t == 0) {
        int best = 0;
        float bv = red[0][0] + b2[0];
        for (int n = 1; n < NBANDS; ++n) {
            const float v = red[n][0] + b2[n];
            if (v > bv) { bv = v; best = n; }
        }
        sel[b] = best;
    }
}

// ---------------------------------------------------------------------------
// Shared MFMA core for the two [64x200]@[200x200]^T projections.
// ---------------------------------------------------------------------------
template<bool BF16OUT>
static __device__ inline void proj_core(
    const float* __restrict__ x0,            // 64 rows x 200 fp32, stride DM
    const unsigned short* __restrict__ Ph,   // packed hi plane
    const unsigned short* __restrict__ Pl,   // packed lo plane
    const float* __restrict__ bias,          // 200
    void* __restrict__ outp)                 // 64 rows x 200 (bf16 or f32)
{
    const int t = threadIdx.x;
    const int w = t >> 6, lane = t & 63;
    const int lm = lane & 15, quad = lane >> 4;
    const int m0 = w * 16;
    const float* xrow = x0 + (size_t)(m0 + lm) * DM;

    f32x4 acc[NTT];
#pragma unroll
    for (int nt = 0; nt < NTT; ++nt) acc[nt] = (f32x4){0.f, 0.f, 0.f, 0.f};

#pragma unroll
    for (int ks = 0; ks < KST; ++ks) {
        const int k0 = ks * 32 + quad * 8;
        bf16x8 a_h = bf8zero(), a_l = bf8zero();
        if (k0 + 8 <= DM) {      // ks=6: only quad 0 (k=192..199) has data
            const float4 xa = *(const float4*)(xrow + k0);
            const float4 xb = *(const float4*)(xrow + k0 + 4);
            split8(xa, xb, a_h, a_l);
        }
        const unsigned short* ph = Ph + ((ks * NTT) << 9) + (lane << 3);
        const unsigned short* pl = Pl + ((ks * NTT) << 9) + (lane << 3);
#pragma unroll
        for (int nt = 0; nt < NTT; ++nt) {
            const bf16x8 b_h = *(const bf16x8*)(ph + (nt << 9));
            const bf16x8 b_l = *(const bf16x8*)(pl + (nt << 9));
            acc[nt] = __builtin_amdgcn_mfma_f32_16x16x32_bf16(a_h, b_h, acc[nt], 0, 0, 0);
            acc[nt] = __builtin_amdgcn_mfma_f32_16x16x32_bf16(a_l, b_h, acc[nt], 0, 0, 0);
            acc[nt] = __builtin_amdgcn_mfma_f32_16x16x32_bf16(a_h, b_l, acc[nt], 0, 0, 0);
        }
    }
#pragma unroll
    for (int nt = 0; nt < NTT; ++nt) {
        const int col = nt * 16 + lm;
        if (col < DM) {
            const float bs = bias[col];
#pragma unroll
            for (int reg = 0; reg < 4; ++reg) {
                const int row = m0 + quad * 4 + reg;
                const float v = acc[nt][reg] + bs;
                if (BF16OUT)
                    ((unsigned short*)outp)[(size_t)row * DM + col] = f2bf(v);
                else
                    ((float*)outp)[(size_t)row * DM + col] = v;
            }
        }
    }
}

// K4: q projection for the selected band -> bf16
__global__ __launch_bounds__(256) void k_qproj_mfma(
    const float* __restrict__ bands, const int* __restrict__ sel,
    const unsigned short* __restrict__ WqHp, const unsigned short* __restrict__ WqLp,
    const float* __restrict__ ipb, unsigned short* __restrict__ qb)
{
    const int b = blockIdx.x;
    const int band = sel[b];
    const float* x0 = bands + (size_t)((band * BATCH + b) * KQN) * DM;
    proj_core<true>(x0, WqHp, WqLp, ipb, qb + (size_t)(b * KQN) * DM);
}

// K7: out = o @ out_w^T + out_b (fp32 out)
__global__ __launch_bounds__(256) void k_outproj_mfma(
    const float* __restrict__ obuf, const unsigned short* __restrict__ OwHp,
    const unsigned short* __restrict__ OwLp, const float* __restrict__ outb,
    float* __restrict__ out)
{
    const int b = blockIdx.x;
    proj_core<false>(obuf + (size_t)(b * KQN) * DM, OwHp, OwLp, outb,
                     out + (size_t)(b * KQN) * DM);
}

// ---------------------------------------------------------------------------
// K5 (rewritten): kv projection, LDS-free proj_core pattern.
// Each block = 64 consecutive kv rows (one contiguous 64x200 fp32 slab of
// bands: M0%320 is a multiple of 64 -> fixed (batch,band), kk=0..63).
// 4 waves x 16 rows x ALL 400 cols (25 N-tiles, 100 VGPR acc). A fragments
// per-lane from global, rounded to bf16 in regs (same numerics as before);
// B from the L2-resident fragment-major Wkv plane (coalesced 1KB/wave).
// bands read EXACTLY once (was 5x); zero LDS; zero barriers.
// ---------------------------------------------------------------------------
__global__ __launch_bounds__(256) void k_kvproj_pk(
    const float* __restrict__ bands, const unsigned short* __restrict__ Wkv,
    const float* __restrict__ ipb, __hip_bfloat16* __restrict__ Kp,
    __hip_bfloat16* __restrict__ Vp)
{
    const int t = threadIdx.x;
    const int w = t >> 6, lane = t & 63;
    const int lm = lane & 15, quad = lane >> 4;
    const int m0 = w * 16;
    const int M0 = blockIdx.x * 64;

    // this wave's A row (16 rows per wave): one batch, one band, kk=row in band
    const int gg = M0 + m0 + lm;
    const int bb = gg / TKV, tk = gg - bb * TKV;
    const int band = tk >> 6, kk = tk & 63;
    const float* xrow = bands + (size_t)((band * BATCH + bb) * KQN + kk) * DM;

    f32x4 acc[NTKV];
#pragma unroll
    for (int nt = 0; nt < NTKV; ++nt) acc[nt] = (f32x4){0.f, 0.f, 0.f, 0.f};

#pragma unroll
    for (int ks = 0; ks < KST; ++ks) {
        const int k0 = ks * 32 + quad * 8;
        bf16x8 a = bf8zero();
        if (k0 + 8 <= DM) {
            const float4 xa = *(const float4*)(xrow + k0);
            const float4 xb = *(const float4*)(xrow + k0 + 4);
            a = round8(xa, xb);
        }
        const unsigned short* pb = Wkv + ((ks * NTKV) << 9) + (lane << 3);
#pragma unroll
        for (int nt = 0; nt < NTKV; ++nt) {
            const bf16x8 b8 = *(const bf16x8*)(pb + (nt << 9));
            acc[nt] = __builtin_amdgcn_mfma_f32_16x16x32_bf16(a, b8, acc[nt], 0, 0, 0);
        }
    }
#pragma unroll
    for (int nt = 0; nt < NTKV; ++nt) {
        const int col = nt * 16 + lm;               // 0..399
        const float bias = ipb[DM + col];
#pragma unroll
        for (int reg = 0; reg < 4; ++reg) {
            const int grow = M0 + m0 + quad * 4 + reg;
            const float v = acc[nt][reg] + bias;
            if (col < DM) Kp[(size_t)grow * DM + col] = __float2bfloat16(v);
            else          Vp[(size_t)grow * DM + (col - DM)] = __float2bfloat16(v);
        }
    }
}

// ---------------------------------------------------------------------------
// K6: MFMA attention per (b, head). Q read as bf16.
// ---------------------------------------------------------------------------
__global__ __launch_bounds__(256) void k_attn(
    const unsigned short* __restrict__ qb, const __hip_bfloat16* __restrict__ Kp,
    const __hip_bfloat16* __restrict__ Vp, float* __restrict__ obuf)
{
    __shared__ __align__(16) unsigned short Qs[64][72];    // [query][k 0..63]
    __shared__ __align__(16) unsigned short KP[320][72];   // [key][k 0..63]
    __shared__ __align__(16) unsigned short Vt[64][328];   // [e][key]
    __shared__ __align__(16) unsigned short Ps[64][328];   // [query][key]
    const int b = blockIdx.x, hh = blockIdx.y;
    const int t = threadIdx.x;

    const unsigned short* qbase = qb + (size_t)(b * KQN) * DM + hh * HD;
    for (int idx = t; idx < 64 * 64; idx += 256) {
        const int r = idx >> 6, e = idx & 63;
        Qs[r][e] = (e < HD) ? qbase[(size_t)r * DM + e] : 0;
    }
    const unsigned short* kbase = (const unsigned short*)Kp + (size_t)b * TKV * DM + hh * HD;
    for (int idx = t; idx < 320 * 25; idx += 256) {
        const int key = idx / 25, g = idx - key * 25;
        *(unsigned int*)&KP[key][g * 2] =
            *(const unsigned int*)(kbase + (size_t)key * DM + g * 2);
    }
    for (int idx = t; idx < 320 * 7; idx += 256) {   // zero k-pad [50,64)
        const int key = idx / 7, g = idx - key * 7;
        *(unsigned int*)&KP[key][50 + g * 2] = 0;
    }
    const unsigned short* vbase = (const unsigned short*)Vp + (size_t)b * TKV * DM + hh * HD;
    for (int idx = t; idx < 320 * 25; idx += 256) {
        const int key = idx / 25, g = idx - key * 25;
        const unsigned int v = *(const unsigned int*)(vbase + (size_t)key * DM + g * 2);
        Vt[g * 2][key]     = (unsigned short)(v & 0xffffu);
        Vt[g * 2 + 1][key] = (unsigned short)(v >> 16);
    }
    __syncthreads();

    const int w = t >> 6, lane = t & 63;
    const int lm = lane & 15, quad = lane >> 4;
    const int m0 = w * 16;

    f32x4 s[20];
#pragma unroll
    for (int nt = 0; nt < 20; ++nt) s[nt] = (f32x4){0.f, 0.f, 0.f, 0.f};
#pragma unroll
    for (int ks = 0; ks < 2; ++ks) {
        const int ka = ks * 32 + quad * 8;
        const bf16x8 a = *(const bf16x8*)&Qs[m0 + lm][ka];
#pragma unroll
        for (int nt = 0; nt < 20; ++nt) {
            const bf16x8 bb8 = *(const bf16x8*)&KP[nt * 16 + lm][ka];
            s[nt] = __builtin_amdgcn_mfma_f32_16x16x32_bf16(a, bb8, s[nt], 0, 0, 0);
        }
    }

    const float scale = 0.14142135623730951f;  // 1/sqrt(50)
    float inv[4];
#pragma unroll
    for (int reg = 0; reg < 4; ++reg) {
        float mx = -1e30f;
#pragma unroll
        for (int nt = 0; nt < 20; ++nt) {
            const float sv = s[nt][reg] * scale;
            s[nt][reg] = sv;
            mx = fmaxf(mx, sv);
        }
#pragma unroll
        for (int off = 1; off < 16; off <<= 1)
            mx = fmaxf(mx, __shfl_xor(mx, off, 64));
        float lsum = 0.f;
#pragma unroll
        for (int nt = 0; nt < 20; ++nt) {
            const float p = __expf(s[nt][reg] - mx);
            s[nt][reg] = p;
            lsum += p;
        }
#pragma unroll
        for (int off = 1; off < 16; off <<= 1)
            lsum += __shfl_xor(lsum, off, 64);
        inv[reg] = 1.f / lsum;
    }
#pragma unroll
    for (int reg = 0; reg < 4; ++reg) {
        const int row = m0 + quad * 4 + reg;
#pragma unroll
        for (int nt = 0; nt < 20; ++nt)
            Ps[row][nt * 16 + lm] = f2bf(s[nt][reg]);
    }
    __syncthreads();

    f32x4 o[4];
#pragma unroll
    for (int nt = 0; nt < 4; ++nt) o[nt] = (f32x4){0.f, 0.f, 0.f, 0.f};
#pragma unroll
    for (int ks = 0; ks < 10; ++ks) {
        const int ka = ks * 32 + quad * 8;
        const bf16x8 a = *(const bf16x8*)&Ps[m0 + lm][ka];
#pragma unroll
        for (int nt = 0; nt < 4; ++nt) {
            const bf16x8 bb8 = *(const bf16x8*)&Vt[nt * 16 + lm][ka];
            o[nt] = __builtin_amdgcn_mfma_f32_16x16x32_bf16(a, bb8, o[nt], 0, 0, 0);
        }
    }
    float* op = obuf + (size_t)(b * KQN) * DM + hh * HD;
#pragma unroll
    for (int nt = 0; nt < 4; ++nt) {
        const int e = nt * 16 + lm;
        if (e < HD) {
#pragma unroll
            for (int reg = 0; reg < 4; ++reg) {
                const int row = m0 + quad * 4 + reg;
                op[(size_t)row * DM + e] = o[nt][reg] * inv[reg];
            }
        }
    }
}

// ---------------------------------------------------------------------------
// Workspace layout (phase-overlapped, peak 184.1 MB < 193 MB):
//   sel  int [512]               @ 0           (2,048)      [live whole run]
//   -- phase 1 (router):
//   part fp32 [20][512][512]     @ 4096        (20,971,520)
//   h    fp32 [512][512]         @ 20,975,616  ( 1,048,576)
//   -- phase 2 (overlaps part/h after argmax):
//   q    bf16 [512][64][200]     @ 4096        (13,107,200)
//   Wkv  bf16 packed             @ 26,218,496  (   179,200)
//   WqHp bf16 packed             @ 26,404,096  (    93,184)
//   WqLp bf16 packed             @ 26,497,280  (    93,184)
//   OwHp bf16 packed             @ 26,590,464  (    93,184)
//   OwLp bf16 packed             @ 26,683,648  (    93,184)
//   Kp   bf16 [512][320][200]    @ 26,776,832  (65,536,000)
//   Vp   bf16 [512][320][200]    @ 92,312,832  (65,536,000)
//   obuf fp32 [512][64][200]     @ 157,848,832 (26,214,400) -> 184,063,232
// ---------------------------------------------------------------------------
extern "C" void kernel_launch(void* const* d_in, const int* in_sizes, int n_in,
                              void* d_out, int out_size, void* d_ws, size_t ws_size,
                              hipStream_t stream)
{
    const float* bands = (const float*)d_in[0];
    const float* w1    = (const float*)d_in[1];
    const float* b1    = (const float*)d_in[2];
    const float* w2    = (const float*)d_in[3];
    const float* b2    = (const float*)d_in[4];
    const float* ipw   = (const float*)d_in[5];
    const float* ipb   = (const float*)d_in[6];
    const float* outw  = (const float*)d_in[7];
    const float* outb  = (const float*)d_in[8];
    float* out = (float*)d_out;

    if (ws_size < (size_t)192940032) return;

    char* ws = (char*)d_ws;
    int*   sel  = (int*)  (ws + 0);
    float* part = (float*)(ws + 4096);
    float* h    = (float*)(ws + 20975616);
    unsigned short* qb = (unsigned short*)(ws + 4096);   // phase 2 (part dead)
    unsigned short* Wkv  = (unsigned short*)(ws + 26218496);
    unsigned short* WqHp = (unsigned short*)(ws + 26404096);
    unsigned short* WqLp = (unsigned short*)(ws + 26497280);
    unsigned short* OwHp = (unsigned short*)(ws + 26590464);
    unsigned short* OwLp = (unsigned short*)(ws + 26683648);
    __hip_bfloat16* Kp = (__hip_bfloat16*)(ws + 26776832);
    __hip_bfloat16* Vp = (__hip_bfloat16*)(ws + 92312832);
    float* obuf = (float*)(ws + 157848832);

    // weight preps (independent of router; regions disjoint from part/h)
    k_wpack_kv<<<KST * NTKV, 256, 0, stream>>>(ipw, Wkv);
    k_wpack<<<dim3(KST * NTT, 2), 256, 0, stream>>>(ipw, outw, WqHp, WqLp, OwHp, OwLp);

    k_router_mfma<<<dim3(8, 8, KSPLIT), 256, 0, stream>>>(bands, w1, part);
    k_reduce_relu<<<(BATCH * HIDW) / 256, 256, 0, stream>>>(part, b1, h);
    k_argmax<<<BATCH, 256, 0, stream>>>(h, w2, b2, sel);
    // ---- phase 2: phase-1 buffers (part/h) are dead from here ----
    k_qproj_mfma<<<BATCH, 256, 0, stream>>>(bands, sel, WqHp, WqLp, ipb, qb);
    k_kvproj_pk<<<2560, 256, 0, stream>>>(bands, Wkv, ipb, Kp, Vp);
    k_attn<<<dim3(BATCH, NHEAD), 256, 0, stream>>>(qb, Kp, Vp, obuf);
    k_outproj_mfma<<<BATCH, 256, 0, stream>>>(obuf, OwHp, OwLp, outb, out);
}

// Round 4
// 782.767 us; speedup vs baseline: 1.2032x; 1.2032x over previous
//
#include <hip/hip_runtime.h>
#include <hip/hip_bf16.h>

// Problem constants
#define NBANDS 5
#define BATCH  512
#define KQN    64     // queries per sample
#define DM     200    // model dim
#define NHEAD  4
#define HD     50     // head dim
#define HIDW   512    // router hidden
#define TKV    320    // NBANDS*KQN keys
#define FIN    64000  // NBANDS*KQN*DM
#define KSPLIT 20
#define KCH    3200   // FIN/KSPLIT
#define RCH    50     // KCH/64 chunks per block
#define NTT    13     // N-tiles of 16 covering 200 (13*16=208)
#define KST    7      // K-steps of 32 covering 200 (7*32=224)
#define NTKV   25     // N-tiles of 16 covering 400

typedef __bf16  bf16x8 __attribute__((ext_vector_type(8)));
typedef float   f32x4  __attribute__((ext_vector_type(4)));

static __device__ inline unsigned short f2bf(float f) {
    __hip_bfloat16 h = __float2bfloat16(f);
    return *reinterpret_cast<unsigned short*>(&h);
}
static __device__ inline float bf2f(unsigned short u) {
    union { unsigned int i; float f; } x;
    x.i = ((unsigned int)u) << 16;
    return x.f;
}
static __device__ inline bf16x8 bf8zero() {
    union { bf16x8 v; unsigned int u[4]; } z;
    z.u[0] = z.u[1] = z.u[2] = z.u[3] = 0u;
    return z.v;
}
// Markidis split of 8 consecutive fp32 into hi/lo bf16x8
static __device__ inline void split8(const float4& a, const float4& b,
                                     bf16x8& hi, bf16x8& lo) {
    union { bf16x8 v; unsigned short u[8]; } H, L;
    const float xs[8] = {a.x, a.y, a.z, a.w, b.x, b.y, b.z, b.w};
#pragma unroll
    for (int i = 0; i < 8; ++i) {
        H.u[i] = f2bf(xs[i]);
        L.u[i] = f2bf(xs[i] - bf2f(H.u[i]));
    }
    hi = H.v; lo = L.v;
}
// plain bf16 round of 8 consecutive fp32
static __device__ inline bf16x8 round8(const float4& a, const float4& b) {
    union { bf16x8 v; unsigned short u[8]; } H;
    const float xs[8] = {a.x, a.y, a.z, a.w, b.x, b.y, b.z, b.w};
#pragma unroll
    for (int i = 0; i < 8; ++i) H.u[i] = f2bf(xs[i]);
    return H.v;
}

// ---------------------------------------------------------------------------
// K1: router GEMM via 3-product split-bf16 MFMA (unchanged from R2/R3).
// ---------------------------------------------------------------------------
__global__ __launch_bounds__(256) void k_router_mfma(
    const float* __restrict__ bands, const float* __restrict__ w1,
    float* __restrict__ part)
{
    __shared__ __align__(16) unsigned short Ah[64][72];
    __shared__ __align__(16) unsigned short Al[64][72];
    __shared__ __align__(16) unsigned short Bh[64][72];
    __shared__ __align__(16) unsigned short Bl[64][72];

    // bijective XCD-cluster swizzle: 1280 blocks = 8 XCD x 160 logical
    const int lin     = (blockIdx.z << 6) + (blockIdx.y << 3) + blockIdx.x;
    const int logical = (lin & 7) * 160 + (lin >> 3);
    const int z   = logical >> 6;          // 0..19
    const int rem = logical & 63;
    const int j0  = (rem & 7) << 6;        // hid tile
    const int b0  = (rem >> 3) << 6;       // batch tile

    const int t  = threadIdx.x;
    const int w  = t >> 6, lane = t & 63;
    const int lm = lane & 15, quad = lane >> 4;
    const int m0 = w * 16;

    const int row0 = t >> 4, c4 = (t & 15) * 4;

    f32x4 acc[4];
#pragma unroll
    for (int nt = 0; nt < 4; ++nt) acc[nt] = (f32x4){0.f, 0.f, 0.f, 0.f};

    const int kbase = z * KCH;
    for (int chunk = 0; chunk < RCH; ++chunk) {
        const int kc = kbase + chunk * 64;
        const int band = kc / 12800;
        const float* abase = bands + (size_t)band * 6540800 + kc + c4;
        const float* bbase = w1 + (size_t)j0 * FIN + kc + c4;
        float4 av[4], bv[4];
#pragma unroll
        for (int r = 0; r < 4; ++r)
            av[r] = *(const float4*)(abase + (size_t)(b0 + row0 + r * 16) * 12800);
#pragma unroll
        for (int r = 0; r < 4; ++r)
            bv[r] = *(const float4*)(bbase + (size_t)(row0 + r * 16) * FIN);
        __syncthreads();   // previous chunk's MFMA LDS reads complete
#pragma unroll
        for (int r = 0; r < 4; ++r) {
            const int row = row0 + r * 16;
            ushort4 hh, ll;
            hh.x = f2bf(av[r].x); ll.x = f2bf(av[r].x - bf2f(hh.x));
            hh.y = f2bf(av[r].y); ll.y = f2bf(av[r].y - bf2f(hh.y));
            hh.z = f2bf(av[r].z); ll.z = f2bf(av[r].z - bf2f(hh.z));
            hh.w = f2bf(av[r].w); ll.w = f2bf(av[r].w - bf2f(hh.w));
            *(ushort4*)&Ah[row][c4] = hh;
            *(ushort4*)&Al[row][c4] = ll;
        }
#pragma unroll
        for (int r = 0; r < 4; ++r) {
            const int row = row0 + r * 16;
            ushort4 hh, ll;
            hh.x = f2bf(bv[r].x); ll.x = f2bf(bv[r].x - bf2f(hh.x));
            hh.y = f2bf(bv[r].y); ll.y = f2bf(bv[r].y - bf2f(hh.y));
            hh.z = f2bf(bv[r].z); ll.z = f2bf(bv[r].z - bf2f(hh.z));
            hh.w = f2bf(bv[r].w); ll.w = f2bf(bv[r].w - bf2f(hh.w));
            *(ushort4*)&Bh[row][c4] = hh;
            *(ushort4*)&Bl[row][c4] = ll;
        }
        __syncthreads();
#pragma unroll
        for (int ks = 0; ks < 2; ++ks) {
            const int ka = ks * 32 + quad * 8;
            const bf16x8 a_h = *(const bf16x8*)&Ah[m0 + lm][ka];
            const bf16x8 a_l = *(const bf16x8*)&Al[m0 + lm][ka];
#pragma unroll
            for (int nt = 0; nt < 4; ++nt) {
                const bf16x8 b_h = *(const bf16x8*)&Bh[nt * 16 + lm][ka];
                const bf16x8 b_l = *(const bf16x8*)&Bl[nt * 16 + lm][ka];
                acc[nt] = __builtin_amdgcn_mfma_f32_16x16x32_bf16(a_h, b_h, acc[nt], 0, 0, 0);
                acc[nt] = __builtin_amdgcn_mfma_f32_16x16x32_bf16(a_l, b_h, acc[nt], 0, 0, 0);
                acc[nt] = __builtin_amdgcn_mfma_f32_16x16x32_bf16(a_h, b_l, acc[nt], 0, 0, 0);
            }
        }
    }
    float* po = part + (size_t)z * (BATCH * HIDW);
#pragma unroll
    for (int nt = 0; nt < 4; ++nt) {
        const int jj = j0 + nt * 16 + lm;
#pragma unroll
        for (int reg = 0; reg < 4; ++reg) {
            const int bb = b0 + m0 + quad * 4 + reg;
            po[(size_t)bb * HIDW + jj] = acc[nt][reg];
        }
    }
}

// ---------------------------------------------------------------------------
// K2: h = relu(sum_z part + b1)
// ---------------------------------------------------------------------------
__global__ __launch_bounds__(256) void k_reduce_relu(
    const float* __restrict__ part, const float* __restrict__ b1,
    float* __restrict__ h)
{
    const int tid = blockIdx.x * 256 + threadIdx.x;  // < BATCH*HIDW
    float s = b1[tid & (HIDW - 1)];
#pragma unroll
    for (int z = 0; z < KSPLIT; ++z) s += part[z * (BATCH * HIDW) + tid];
    h[tid] = fmaxf(s, 0.f);
}

// ---------------------------------------------------------------------------
// K2c: pack wq (ipw rows 0..199) and out_w into FRAGMENT-MAJOR Markidis
// hi/lo bf16 planes.
// ---------------------------------------------------------------------------
__global__ __launch_bounds__(256) void k_wpack(
    const float* __restrict__ ipw, const float* __restrict__ outw,
    unsigned short* __restrict__ WqHp, unsigned short* __restrict__ WqLp,
    unsigned short* __restrict__ OwHp, unsigned short* __restrict__ OwLp)
{
    const int p = blockIdx.x;          // 0..90 : ks*13+nt
    const int ks = p / NTT, nt = p - ks * NTT;
    const int t = threadIdx.x;
    const int lane = t >> 2, e0 = (t & 3) * 2;
    const int lm = lane & 15, quad = lane >> 4;
    const int row = nt * 16 + lm;
    const int k  = ks * 32 + quad * 8 + e0;
    const float* src = (blockIdx.y == 0) ? ipw : outw;   // wq = ipw rows 0..199
    unsigned short* dh = (blockIdx.y == 0) ? WqHp : OwHp;
    unsigned short* dl = (blockIdx.y == 0) ? WqLp : OwLp;
    float v0 = 0.f, v1 = 0.f;
    if (row < DM && k < DM) {          // k even, so k<200 => k+1<=199 valid
        v0 = src[(size_t)row * DM + k];
        v1 = src[(size_t)row * DM + k + 1];
    }
    const int off = (p << 9) + (lane << 3) + e0;
    const unsigned short h0 = f2bf(v0), h1 = f2bf(v1);
    dh[off]     = h0;
    dh[off + 1] = h1;
    dl[off]     = f2bf(v0 - bf2f(h0));
    dl[off + 1] = f2bf(v1 - bf2f(h1));
}

// ---------------------------------------------------------------------------
// K2d: pack wk|wv (ipw rows 200..599) into ONE fragment-major bf16 plane.
// elem ((ks*25+nt)*64 + lane)*8 + e = ipw[200 + nt*16+lm][ks*32+quad*8+e],
// zero past k=200. Plane = 7*25*512 ushorts = 179,200 B (L2-resident).
// Per-ks slab (25 KB) is CONTIGUOUS -> linear async LDS staging downstream.
// ---------------------------------------------------------------------------
__global__ __launch_bounds__(256) void k_wpack_kv(
    const float* __restrict__ ipw, unsigned short* __restrict__ Wkv)
{
    const int p = blockIdx.x;          // 0..174 : ks*25+nt
    const int ks = p / NTKV, nt = p - ks * NTKV;
    const int t = threadIdx.x;
    const int lane = t >> 2, e0 = (t & 3) * 2;
    const int lm = lane & 15, quad = lane >> 4;
    const int row = nt * 16 + lm;                 // 0..399, always valid
    const int k  = ks * 32 + quad * 8 + e0;
    float v0 = 0.f, v1 = 0.f;
    if (k < DM) {
        v0 = ipw[(size_t)(DM + row) * DM + k];
        v1 = ipw[(size_t)(DM + row) * DM + k + 1];
    }
    const int off = (p << 9) + (lane << 3) + e0;
    Wkv[off]     = f2bf(v0);
    Wkv[off + 1] = f2bf(v1);
}

// ---------------------------------------------------------------------------
// K3: logits = h @ w2^T + b2 ; sel = argmax
// ---------------------------------------------------------------------------
__global__ __launch_bounds__(256) void k_argmax(
    const float* __restrict__ h, const float* __restrict__ w2,
    const float* __restrict__ b2, int* __restrict__ sel)
{
    __shared__ float red[NBANDS][256];
    const int b = blockIdx.x, t = threadIdx.x;
    float acc[NBANDS] = {0.f, 0.f, 0.f, 0.f, 0.f};
    for (int j = t; j < HIDW; j += 256) {
        const float hv = h[b * HIDW + j];
#pragma unroll
        for (int n = 0; n < NBANDS; ++n)
            acc[n] = fmaf(hv, w2[n * HIDW + j], acc[n]);
    }
#pragma unroll
    for (int n = 0; n < NBANDS; ++n) red[n][t] = acc[n];
    __syncthreads();
    for (int s = 128; s > 0; s >>= 1) {
        if (t < s) {
#pragma unroll
            for (int n = 0; n < NBANDS; ++n) red[n][t] += red[n][t + s];
        }
        __syncthreads();
    }
    if (t == 0) {
        int best = 0;
        float bv = red[0][0] + b2[0];
        for (int n = 1; n < NBANDS; ++n) {
            const float v = red[n][0] + b2[n];
            if (v > bv) { bv = v; best = n; }
        }
        sel[b] = best;
    }
}

// ---------------------------------------------------------------------------
// Shared MFMA core for the two [64x200]@[200x200]^T projections.
// ---------------------------------------------------------------------------
template<bool BF16OUT>
static __device__ inline void proj_core(
    const float* __restrict__ x0,            // 64 rows x 200 fp32, stride DM
    const unsigned short* __restrict__ Ph,   // packed hi plane
    const unsigned short* __restrict__ Pl,   // packed lo plane
    const float* __restrict__ bias,          // 200
    void* __restrict__ outp)                 // 64 rows x 200 (bf16 or f32)
{
    const int t = threadIdx.x;
    const int w = t >> 6, lane = t & 63;
    const int lm = lane & 15, quad = lane >> 4;
    const int m0 = w * 16;
    const float* xrow = x0 + (size_t)(m0 + lm) * DM;

    f32x4 acc[NTT];
#pragma unroll
    for (int nt = 0; nt < NTT; ++nt) acc[nt] = (f32x4){0.f, 0.f, 0.f, 0.f};

#pragma unroll
    for (int ks = 0; ks < KST; ++ks) {
        const int k0 = ks * 32 + quad * 8;
        bf16x8 a_h = bf8zero(), a_l = bf8zero();
        if (k0 + 8 <= DM) {      // ks=6: only quad 0 (k=192..199) has data
            const float4 xa = *(const float4*)(xrow + k0);
            const float4 xb = *(const float4*)(xrow + k0 + 4);
            split8(xa, xb, a_h, a_l);
        }
        const unsigned short* ph = Ph + ((ks * NTT) << 9) + (lane << 3);
        const unsigned short* pl = Pl + ((ks * NTT) << 9) + (lane << 3);
#pragma unroll
        for (int nt = 0; nt < NTT; ++nt) {
            const bf16x8 b_h = *(const bf16x8*)(ph + (nt << 9));
            const bf16x8 b_l = *(const bf16x8*)(pl + (nt << 9));
            acc[nt] = __builtin_amdgcn_mfma_f32_16x16x32_bf16(a_h, b_h, acc[nt], 0, 0, 0);
            acc[nt] = __builtin_amdgcn_mfma_f32_16x16x32_bf16(a_l, b_h, acc[nt], 0, 0, 0);
            acc[nt] = __builtin_amdgcn_mfma_f32_16x16x32_bf16(a_h, b_l, acc[nt], 0, 0, 0);
        }
    }
#pragma unroll
    for (int nt = 0; nt < NTT; ++nt) {
        const int col = nt * 16 + lm;
        if (col < DM) {
            const float bs = bias[col];
#pragma unroll
            for (int reg = 0; reg < 4; ++reg) {
                const int row = m0 + quad * 4 + reg;
                const float v = acc[nt][reg] + bs;
                if (BF16OUT)
                    ((unsigned short*)outp)[(size_t)row * DM + col] = f2bf(v);
                else
                    ((float*)outp)[(size_t)row * DM + col] = v;
            }
        }
    }
}

// K4: q projection for the selected band -> bf16
__global__ __launch_bounds__(256) void k_qproj_mfma(
    const float* __restrict__ bands, const int* __restrict__ sel,
    const unsigned short* __restrict__ WqHp, const unsigned short* __restrict__ WqLp,
    const float* __restrict__ ipb, unsigned short* __restrict__ qb)
{
    const int b = blockIdx.x;
    const int band = sel[b];
    const float* x0 = bands + (size_t)((band * BATCH + b) * KQN) * DM;
    proj_core<true>(x0, WqHp, WqLp, ipb, qb + (size_t)(b * KQN) * DM);
}

// K7: out = o @ out_w^T + out_b (fp32 out)
__global__ __launch_bounds__(256) void k_outproj_mfma(
    const float* __restrict__ obuf, const unsigned short* __restrict__ OwHp,
    const unsigned short* __restrict__ OwLp, const float* __restrict__ outb,
    float* __restrict__ out)
{
    const int b = blockIdx.x;
    proj_core<false>(obuf + (size_t)(b * KQN) * DM, OwHp, OwLp, outb,
                     out + (size_t)(b * KQN) * DM);
}

// ---------------------------------------------------------------------------
// K5 (v3): kv projection — A in registers (bands read exactly once), B via
// ASYNC double-buffered LDS staging (global_load_lds width=16).
// R3's LDS-free version failed: acc alone = 100 VGPR left ~8 regs -> zero
// prefetch depth, every B load a serialized L2 round trip (MfmaUtil 4%).
// Fix: the 25 KB/ks B slab is identical for all 4 waves -> stage it ONCE per
// block asynchronously into LDS (no VGPR round trip), double-buffered so the
// DMA of slab ks+1 flies under the 25 MFMAs of slab ks. LDS 2x25 KB = 51.2 KB
// -> 3 blocks/CU. B ds_read: 64 lanes span a contiguous 1 KB row (2-way bank
// aliasing = free). Numerics identical to R3 (same rounding, same acc order).
// ---------------------------------------------------------------------------
__global__ __launch_bounds__(256) void k_kvproj_lds(
    const float* __restrict__ bands, const unsigned short* __restrict__ Wkv,
    const float* __restrict__ ipb, __hip_bfloat16* __restrict__ Kp,
    __hip_bfloat16* __restrict__ Vp)
{
    __shared__ __align__(16) unsigned short Bs[2][NTKV * 512];  // 2 x 25 KB
    const int t = threadIdx.x;
    const int w = t >> 6, lane = t & 63;
    const int lm = lane & 15, quad = lane >> 4;
    const int m0 = w * 16;
    const int M0 = blockIdx.x * 64;

    // this wave's A row: one batch, one band, kk = row within band
    const int gg = M0 + m0 + lm;
    const int bb = gg / TKV, tk = gg - bb * TKV;
    const int band = tk >> 6, kk = tk & 63;
    const float* xrow = bands + (size_t)((band * BATCH + bb) * KQN + kk) * DM;

    // ---- issue ALL A loads up front (13-14 independent float4 -> max MLP),
    //      then convert once to 7 bf16x8 fragments held in registers ----
    float4 ar[2 * KST];
#pragma unroll
    for (int ks = 0; ks < KST; ++ks) {
        const int k0 = ks * 32 + quad * 8;
        if (k0 + 8 <= DM) {
            ar[2 * ks]     = *(const float4*)(xrow + k0);
            ar[2 * ks + 1] = *(const float4*)(xrow + k0 + 4);
        }
    }
    bf16x8 a[KST];
#pragma unroll
    for (int ks = 0; ks < KST; ++ks) {
        const int k0 = ks * 32 + quad * 8;
        a[ks] = (k0 + 8 <= DM) ? round8(ar[2 * ks], ar[2 * ks + 1]) : bf8zero();
    }

    // async stage of one 25 KB slab (1600 x 16 B) into Bs[buf]
    auto stage = [&](int ks, int buf) {
        const unsigned short* src = Wkv + ((ks * NTKV) << 9);
#pragma unroll
        for (int pass = 0; pass < 6; ++pass) {
            const int i = pass * 256 + t;              // 16B-unit index
            __builtin_amdgcn_global_load_lds(
                (const __attribute__((address_space(1))) unsigned int*)(src + (size_t)i * 8),
                (__attribute__((address_space(3))) unsigned int*)&Bs[buf][(pass * 256 + w * 64) * 8],
                16, 0, 0);
        }
        if (t < 64) {                                   // tail: wave 0 only
            __builtin_amdgcn_global_load_lds(
                (const __attribute__((address_space(1))) unsigned int*)(src + (size_t)(1536 + lane) * 8),
                (__attribute__((address_space(3))) unsigned int*)&Bs[buf][1536 * 8],
                16, 0, 0);
        }
    };

    f32x4 acc[NTKV];
#pragma unroll
    for (int nt = 0; nt < NTKV; ++nt) acc[nt] = (f32x4){0.f, 0.f, 0.f, 0.f};

    stage(0, 0);
    __syncthreads();               // drains vmcnt -> Bs[0] ready
#pragma unroll
    for (int ks = 0; ks < KST; ++ks) {
        if (ks + 1 < KST) stage(ks + 1, (ks + 1) & 1);   // DMA flies under MFMAs
        const unsigned short* bs = &Bs[ks & 1][lane * 8];
#pragma unroll
        for (int nt = 0; nt < NTKV; ++nt) {
            const bf16x8 b8 = *(const bf16x8*)(bs + (nt << 9));
            acc[nt] = __builtin_amdgcn_mfma_f32_16x16x32_bf16(a[ks], b8, acc[nt], 0, 0, 0);
        }
        __syncthreads();           // next slab staged + all waves done with cur
    }

#pragma unroll
    for (int nt = 0; nt < NTKV; ++nt) {
        const int col = nt * 16 + lm;               // 0..399
        const float bias = ipb[DM + col];
#pragma unroll
        for (int reg = 0; reg < 4; ++reg) {
            const int grow = M0 + m0 + quad * 4 + reg;
            const float v = acc[nt][reg] + bias;
            if (col < DM) Kp[(size_t)grow * DM + col] = __float2bfloat16(v);
            else          Vp[(size_t)grow * DM + (col - DM)] = __float2bfloat16(v);
        }
    }
}

// ---------------------------------------------------------------------------
// K6: MFMA attention per (b, head). Q read as bf16.
// ---------------------------------------------------------------------------
__global__ __launch_bounds__(256) void k_attn(
    const unsigned short* __restrict__ qb, const __hip_bfloat16* __restrict__ Kp,
    const __hip_bfloat16* __restrict__ Vp, float* __restrict__ obuf)
{
    __shared__ __align__(16) unsigned short Qs[64][72];    // [query][k 0..63]
    __shared__ __align__(16) unsigned short KP[320][72];   // [key][k 0..63]
    __shared__ __align__(16) unsigned short Vt[64][328];   // [e][key]
    __shared__ __align__(16) unsigned short Ps[64][328];   // [query][key]
    const int b = blockIdx.x, hh = blockIdx.y;
    const int t = threadIdx.x;

    const unsigned short* qbase = qb + (size_t)(b * KQN) * DM + hh * HD;
    for (int idx = t; idx < 64 * 64; idx += 256) {
        const int r = idx >> 6, e = idx & 63;
        Qs[r][e] = (e < HD) ? qbase[(size_t)r * DM + e] : 0;
    }
    const unsigned short* kbase = (const unsigned short*)Kp + (size_t)b * TKV * DM + hh * HD;
    for (int idx = t; idx < 320 * 25; idx += 256) {
        const int key = idx / 25, g = idx - key * 25;
        *(unsigned int*)&KP[key][g * 2] =
            *(const unsigned int*)(kbase + (size_t)key * DM + g * 2);
    }
    for (int idx = t; idx < 320 * 7; idx += 256) {   // zero k-pad [50,64)
        const int key = idx / 7, g = idx - key * 7;
        *(unsigned int*)&KP[key][50 + g * 2] = 0;
    }
    const unsigned short* vbase = (const unsigned short*)Vp + (size_t)b * TKV * DM + hh * HD;
    for (int idx = t; idx < 320 * 25; idx += 256) {
        const int key = idx / 25, g = idx - key * 25;
        const unsigned int v = *(const unsigned int*)(vbase + (size_t)key * DM + g * 2);
        Vt[g * 2][key]     = (unsigned short)(v & 0xffffu);
        Vt[g * 2 + 1][key] = (unsigned short)(v >> 16);
    }
    __syncthreads();

    const int w = t >> 6, lane = t & 63;
    const int lm = lane & 15, quad = lane >> 4;
    const int m0 = w * 16;

    f32x4 s[20];
#pragma unroll
    for (int nt = 0; nt < 20; ++nt) s[nt] = (f32x4){0.f, 0.f, 0.f, 0.f};
#pragma unroll
    for (int ks = 0; ks < 2; ++ks) {
        const int ka = ks * 32 + quad * 8;
        const bf16x8 a = *(const bf16x8*)&Qs[m0 + lm][ka];
#pragma unroll
        for (int nt = 0; nt < 20; ++nt) {
            const bf16x8 bb8 = *(const bf16x8*)&KP[nt * 16 + lm][ka];
            s[nt] = __builtin_amdgcn_mfma_f32_16x16x32_bf16(a, bb8, s[nt], 0, 0, 0);
        }
    }

    const float scale = 0.14142135623730951f;  // 1/sqrt(50)
    float inv[4];
#pragma unroll
    for (int reg = 0; reg < 4; ++reg) {
        float mx = -1e30f;
#pragma unroll
        for (int nt = 0; nt < 20; ++nt) {
            const float sv = s[nt][reg] * scale;
            s[nt][reg] = sv;
            mx = fmaxf(mx, sv);
        }
#pragma unroll
        for (int off = 1; off < 16; off <<= 1)
            mx = fmaxf(mx, __shfl_xor(mx, off, 64));
        float lsum = 0.f;
#pragma unroll
        for (int nt = 0; nt < 20; ++nt) {
            const float p = __expf(s[nt][reg] - mx);
            s[nt][reg] = p;
            lsum += p;
        }
#pragma unroll
        for (int off = 1; off < 16; off <<= 1)
            lsum += __shfl_xor(lsum, off, 64);
        inv[reg] = 1.f / lsum;
    }
#pragma unroll
    for (int reg = 0; reg < 4; ++reg) {
        const int row = m0 + quad * 4 + reg;
#pragma unroll
        for (int nt = 0; nt < 20; ++nt)
            Ps[row][nt * 16 + lm] = f2bf(s[nt][reg]);
    }
    __syncthreads();

    f32x4 o[4];
#pragma unroll
    for (int nt = 0; nt < 4; ++nt) o[nt] = (f32x4){0.f, 0.f, 0.f, 0.f};
#pragma unroll
    for (int ks = 0; ks < 10; ++ks) {
        const int ka = ks * 32 + quad * 8;
        const bf16x8 a = *(const bf16x8*)&Ps[m0 + lm][ka];
#pragma unroll
        for (int nt = 0; nt < 4; ++nt) {
            const bf16x8 bb8 = *(const bf16x8*)&Vt[nt * 16 + lm][ka];
            o[nt] = __builtin_amdgcn_mfma_f32_16x16x32_bf16(a, bb8, o[nt], 0, 0, 0);
        }
    }
    float* op = obuf + (size_t)(b * KQN) * DM + hh * HD;
#pragma unroll
    for (int nt = 0; nt < 4; ++nt) {
        const int e = nt * 16 + lm;
        if (e < HD) {
#pragma unroll
            for (int reg = 0; reg < 4; ++reg) {
                const int row = m0 + quad * 4 + reg;
                op[(size_t)row * DM + e] = o[nt][reg] * inv[reg];
            }
        }
    }
}

// ---------------------------------------------------------------------------
// Workspace layout (phase-overlapped, peak 184.1 MB < 193 MB):
//   sel  int [512]               @ 0           (2,048)      [live whole run]
//   -- phase 1 (router):
//   part fp32 [20][512][512]     @ 4096        (20,971,520)
//   h    fp32 [512][512]         @ 20,975,616  ( 1,048,576)
//   -- phase 2 (overlaps part/h after argmax):
//   q    bf16 [512][64][200]     @ 4096        (13,107,200)
//   Wkv  bf16 packed             @ 26,218,496  (   179,200)
//   WqHp bf16 packed             @ 26,404,096  (    93,184)
//   WqLp bf16 packed             @ 26,497,280  (    93,184)
//   OwHp bf16 packed             @ 26,590,464  (    93,184)
//   OwLp bf16 packed             @ 26,683,648  (    93,184)
//   Kp   bf16 [512][320][200]    @ 26,776,832  (65,536,000)
//   Vp   bf16 [512][320][200]    @ 92,312,832  (65,536,000)
//   obuf fp32 [512][64][200]     @ 157,848,832 (26,214,400) -> 184,063,232
// ---------------------------------------------------------------------------
extern "C" void kernel_launch(void* const* d_in, const int* in_sizes, int n_in,
                              void* d_out, int out_size, void* d_ws, size_t ws_size,
                              hipStream_t stream)
{
    const float* bands = (const float*)d_in[0];
    const float* w1    = (const float*)d_in[1];
    const float* b1    = (const float*)d_in[2];
    const float* w2    = (const float*)d_in[3];
    const float* b2    = (const float*)d_in[4];
    const float* ipw   = (const float*)d_in[5];
    const float* ipb   = (const float*)d_in[6];
    const float* outw  = (const float*)d_in[7];
    const float* outb  = (const float*)d_in[8];
    float* out = (float*)d_out;

    if (ws_size < (size_t)192940032) return;

    char* ws = (char*)d_ws;
    int*   sel  = (int*)  (ws + 0);
    float* part = (float*)(ws + 4096);
    float* h    = (float*)(ws + 20975616);
    unsigned short* qb = (unsigned short*)(ws + 4096);   // phase 2 (part dead)
    unsigned short* Wkv  = (unsigned short*)(ws + 26218496);
    unsigned short* WqHp = (unsigned short*)(ws + 26404096);
    unsigned short* WqLp = (unsigned short*)(ws + 26497280);
    unsigned short* OwHp = (unsigned short*)(ws + 26590464);
    unsigned short* OwLp = (unsigned short*)(ws + 26683648);
    __hip_bfloat16* Kp = (__hip_bfloat16*)(ws + 26776832);
    __hip_bfloat16* Vp = (__hip_bfloat16*)(ws + 92312832);
    float* obuf = (float*)(ws + 157848832);

    // weight preps (independent of router; regions disjoint from part/h)
    k_wpack_kv<<<KST * NTKV, 256, 0, stream>>>(ipw, Wkv);
    k_wpack<<<dim3(KST * NTT, 2), 256, 0, stream>>>(ipw, outw, WqHp, WqLp, OwHp, OwLp);

    k_router_mfma<<<dim3(8, 8, KSPLIT), 256, 0, stream>>>(bands, w1, part);
    k_reduce_relu<<<(BATCH * HIDW) / 256, 256, 0, stream>>>(part, b1, h);
    k_argmax<<<BATCH, 256, 0, stream>>>(h, w2, b2, sel);
    // ---- phase 2: phase-1 buffers (part/h) are dead from here ----
    k_qproj_mfma<<<BATCH, 256, 0, stream>>>(bands, sel, WqHp, WqLp, ipb, qb);
    k_kvproj_lds<<<2560, 256, 0, stream>>>(bands, Wkv, ipb, Kp, Vp);
    k_attn<<<dim3(BATCH, NHEAD), 256, 0, stream>>>(qb, Kp, Vp, obuf);
    k_outproj_mfma<<<BATCH, 256, 0, stream>>>(obuf, OwHp, OwLp, outb, out);
}